// Round 10
// baseline (426.230 us; speedup 1.0000x reference)
//
#include <hip/hip_runtime.h>
#include <hip/hip_bf16.h>
#include <hip/hip_cooperative_groups.h>
#include <stdint.h>

namespace cg = cooperative_groups;

constexpr int IN_DIM  = 256;
constexpr int OUT_DIM = 256;
constexpr int HEADS   = 4;
constexpr int HEAD_DIM = 64;
constexpr float NEG_SLOPE = 0.2f;

typedef __attribute__((ext_vector_type(8))) short bf16x8;
typedef __attribute__((ext_vector_type(4))) float f32x4;

static __device__ __forceinline__ unsigned short f2bf(float f) {
  union { float f; uint32_t u; } v; v.f = f;
  uint32_t u = v.u;
  return (unsigned short)((u + 0x7fffu + ((u >> 16) & 1u)) >> 16);  // RNE
}

// ---------------- prep: zero counts + Wb=bf16(W) (blocks 0..31) + csrc (block 32) ----------------
__global__ __launch_bounds__(256) void k_prep(
    const float* __restrict__ W, const float* __restrict__ b,
    const float* __restrict__ a_src, const float* __restrict__ a_dst,
    float* __restrict__ csrc, unsigned short* __restrict__ Wb,
    int* __restrict__ counts, int N) {
  int bid = blockIdx.x, t = threadIdx.x;
  int i = bid * 256 + t;
  if (i < N) counts[i] = 0;
  if (bid < 32) {
    int base = bid * 2048 + t * 8;
    float4 f0 = *(const float4*)(W + base);
    float4 f1 = *(const float4*)(W + base + 4);
    union { unsigned short us[8]; uint4 u4; } pk;
    pk.us[0]=f2bf(f0.x); pk.us[1]=f2bf(f0.y); pk.us[2]=f2bf(f0.z); pk.us[3]=f2bf(f0.w);
    pk.us[4]=f2bf(f1.x); pk.us[5]=f2bf(f1.y); pk.us[6]=f2bf(f1.z); pk.us[7]=f2bf(f1.w);
    *(uint4*)(Wb + base) = pk.u4;
  } else if (bid == 32 && t < 8) {
    int hh = t & 3;
    const float* a = (t < 4 ? a_src : a_dst) + hh * HEAD_DIM;
    float cs = 0.f;
    for (int d = 0; d < HEAD_DIM; ++d) cs += b[hh * HEAD_DIM + d] * a[d];
    csrc[t] = cs;
  }
}

// ---------------- MFMA GEMM: Wh = bf16( h @ W^T + b ), fused alpha + fused hist ----------------
// tile 64(M) x 256(N), K=256 in 4 chunks of 64. wave w owns cols [w*64,w*64+64) == head w.
// A+B staged in LDS (40KB, single-buffered); 16B chunks XOR-swizzled (pos = chunk^(row&7)).
// T14 async-split on A: next chunk's loads issue into registers before compute; the
// convert+LDS-write lands after the post-compute barrier (latency hidden under MFMAs).
__global__ __launch_bounds__(256) void k_gemm_mfma(
    const float* __restrict__ h, const unsigned short* __restrict__ Wb,
    const float* __restrict__ b,
    const float* __restrict__ a_src, const float* __restrict__ a_dst,
    const float* __restrict__ csrc,
    unsigned short* __restrict__ Wh,
    float* __restrict__ asrc, float* __restrict__ adst,
    const int* __restrict__ idx_i, int* __restrict__ counts, int N, int E) {
  __shared__ unsigned short lds[20480];  // A @ 0 (8KB), B @ 4096 (32KB)
  const int t = threadIdx.x;
  const int w = t >> 6, l = t & 63;
  const int lm = l & 15, g = l >> 4;
  const int r0 = blockIdx.x * 64;

  const int arow = t >> 2;
  int growA = r0 + arow; if (growA > N - 1) growA = N - 1;
  const float* aptr = h + (size_t)growA * 256;

  f32x4 acc[4][4];
  const f32x4 fz = {0.f, 0.f, 0.f, 0.f};
#pragma unroll
  for (int fm = 0; fm < 4; ++fm)
#pragma unroll
    for (int fn = 0; fn < 4; ++fn) acc[fm][fn] = fz;

  float breg[4], asg[4], adg[4];
#pragma unroll
  for (int fn = 0; fn < 4; ++fn) {
    breg[fn] = b[w * 64 + fn * 16 + lm];
    asg[fn]  = a_src[w * 64 + fn * 16 + lm];
    adg[fn]  = a_dst[w * 64 + fn * 16 + lm];
  }

  f32x4 apre[4];  // prefetched A: 2 chunks x 2 f32x4

  auto loadA = [&](int ch) {
    int k0 = ch * 64;
#pragma unroll
    for (int cc = 0; cc < 2; ++cc) {
      int c = (t & 3) * 2 + cc;
      apre[cc * 2 + 0] = *(const f32x4*)(aptr + k0 + c * 8);
      apre[cc * 2 + 1] = *(const f32x4*)(aptr + k0 + c * 8 + 4);
    }
  };

  auto writeA = [&]() {
    unsigned short* dstbase = lds + arow * 64;
#pragma unroll
    for (int cc = 0; cc < 2; ++cc) {
      int c = (t & 3) * 2 + cc;
      union { unsigned short us[8]; bf16x8 v; } pk;
      f32x4 f0 = apre[cc * 2 + 0], f1 = apre[cc * 2 + 1];
      pk.us[0]=f2bf(f0.x); pk.us[1]=f2bf(f0.y); pk.us[2]=f2bf(f0.z); pk.us[3]=f2bf(f0.w);
      pk.us[4]=f2bf(f1.x); pk.us[5]=f2bf(f1.y); pk.us[6]=f2bf(f1.z); pk.us[7]=f2bf(f1.w);
      *(bf16x8*)(dstbase + ((c ^ (arow & 7)) * 8)) = pk.v;
    }
  };

  auto stageB = [&](int ch) {
    int k0 = ch * 64;
    unsigned short* Bbase = lds + 4096;
    int c  = l & 7;
    int rs = l >> 3;
#pragma unroll
    for (int i = 0; i < 8; ++i) {
      int row = w * 64 + i * 8 + rs;  // row&7 == rs
      bf16x8 v = *(const bf16x8*)(Wb + (size_t)row * 256 + k0 + c * 8);
      *(bf16x8*)(Bbase + row * 64 + ((c ^ rs) * 8)) = v;
    }
  };

  auto compute = [&]() {
    const unsigned short* A = lds;
    const unsigned short* B = lds + 4096;
#pragma unroll
    for (int ks = 0; ks < 2; ++ks) {
      bf16x8 af[4], bfr[4];
#pragma unroll
      for (int fm = 0; fm < 4; ++fm) {
        int row = fm * 16 + lm;
        af[fm] = *(const bf16x8*)(A + row * 64 + (((ks * 4 + g) ^ (row & 7)) * 8));
      }
#pragma unroll
      for (int fn = 0; fn < 4; ++fn) {
        int row = w * 64 + fn * 16 + lm;
        bfr[fn] = *(const bf16x8*)(B + row * 64 + (((ks * 4 + g) ^ (row & 7)) * 8));
      }
#pragma unroll
      for (int fm = 0; fm < 4; ++fm)
#pragma unroll
        for (int fn = 0; fn < 4; ++fn)
          acc[fm][fn] = __builtin_amdgcn_mfma_f32_16x16x32_bf16(
              af[fm], bfr[fn], acc[fm][fn], 0, 0, 0);
    }
  };

  loadA(0); writeA(); stageB(0);
  __syncthreads();
#pragma unroll
  for (int ch = 0; ch < 4; ++ch) {
    if (ch < 3) loadA(ch + 1);
    compute();
    __syncthreads();
    if (ch < 3) {
      writeA();
      stageB(ch + 1);
      __syncthreads();
    }
  }

  // ---- epilogue 1: Wh store.  D row = (l>>4)*4+reg, col = l&15 ----
#pragma unroll
  for (int fm = 0; fm < 4; ++fm) {
#pragma unroll
    for (int r = 0; r < 4; ++r) {
      int grow = r0 + fm * 16 + g * 4 + r;
      if (grow < N) {
        size_t rowoff = (size_t)grow * 256;
#pragma unroll
        for (int fn = 0; fn < 4; ++fn) {
          int col = w * 64 + fn * 16 + lm;
          Wh[rowoff + col] = f2bf(acc[fm][fn][r] + breg[fn]);
        }
      }
    }
  }

  // ---- epilogue 2: fused alpha (exact fp32 accumulation; wave w == head w) ----
  float cs = csrc[w], cd = csrc[4 + w];
#pragma unroll
  for (int fm = 0; fm < 4; ++fm) {
#pragma unroll
    for (int r = 0; r < 4; ++r) {
      float ps = acc[fm][0][r] * asg[0] + acc[fm][1][r] * asg[1]
               + acc[fm][2][r] * asg[2] + acc[fm][3][r] * asg[3];
      float pd = acc[fm][0][r] * adg[0] + acc[fm][1][r] * adg[1]
               + acc[fm][2][r] * adg[2] + acc[fm][3][r] * adg[3];
#pragma unroll
      for (int off = 1; off < 16; off <<= 1) {
        ps += __shfl_xor(ps, off, 64);
        pd += __shfl_xor(pd, off, 64);
      }
      if (lm == 0) {
        int grow = r0 + fm * 16 + g * 4 + r;
        if (grow < N) {
          asrc[grow * 4 + w] = ps + cs;
          adst[grow * 4 + w] = pd + cd;
        }
      }
    }
  }

  // ---- fused hist: this block's slice of the edge list (counts pre-zeroed) ----
  {
    long long nb = gridDim.x;
    long long e0 = (long long)blockIdx.x * E / nb;
    long long e1 = ((long long)blockIdx.x + 1) * E / nb;
    for (long long e = e0 + t; e < e1; e += 256)
      atomicAdd(&counts[idx_i[e]], 1);
  }
}

// ---------------- cooperative CSR build: scan chunks -> apply prefix -> scatter ----------------
// Grid must be co-resident (1024 blocks x 256 thr: 4 blk/CU, ~1KB LDS - safe).
// Phase 1: per-1024-element exclusive scan of counts into offsets (+ chunk totals in bsum).
// Phase 2: every working block redundantly scans bsum in LDS, adds its chunk prefix.
// Phase 3: grid-stride scatter; afterwards offsets[i] == END of segment i.
__global__ __launch_bounds__(256) void k_csr(
    const int* __restrict__ idx_i, const int* __restrict__ idx_j,
    const int* __restrict__ counts, int* __restrict__ offsets,
    int* __restrict__ bsum, int* __restrict__ csr_j, int N, int E) {
  cg::grid_group grid = cg::this_grid();
  const int t = threadIdx.x, bid = blockIdx.x;
  const int nthreads = gridDim.x * 256;
  const int nchunk = (N + 1023) >> 10;
  __shared__ int s[256];

  // phase 1: chunk-local exclusive scan
  if (bid < nchunk) {
    int base = bid * 1024 + t * 4;
    int v[4], sum = 0;
#pragma unroll
    for (int k = 0; k < 4; ++k) {
      v[k] = (base + k < N) ? counts[base + k] : 0;
      sum += v[k];
    }
    s[t] = sum;
    __syncthreads();
    for (int off = 1; off < 256; off <<= 1) {
      int x = (t >= off) ? s[t - off] : 0;
      __syncthreads();
      s[t] += x;
      __syncthreads();
    }
    int pre = s[t] - sum;
#pragma unroll
    for (int k = 0; k < 4; ++k) {
      if (base + k < N) offsets[base + k] = pre;
      pre += v[k];
    }
    if (t == 255) bsum[bid] = s[255];
  }
  grid.sync();

  // phase 2: apply chunk prefix
  if (bid < nchunk) {
    int v2 = (t < nchunk) ? bsum[t] : 0;
    s[t] = v2;
    __syncthreads();
    for (int off = 1; off < 256; off <<= 1) {
      int x = (t >= off) ? s[t - off] : 0;
      __syncthreads();
      s[t] += x;   // inclusive scan of chunk totals
      __syncthreads();
    }
    int add = (bid > 0) ? s[bid - 1] : 0;
    int base = bid * 1024 + t * 4;
#pragma unroll
    for (int k = 0; k < 4; ++k)
      if (base + k < N) offsets[base + k] += add;
  }
  grid.sync();

  // phase 3: scatter (cursor-free atomic post-increment)
  for (int e = bid * 256 + t; e < E; e += nthreads) {
    int i = idx_i[e];
    int p = atomicAdd(&offsets[i], 1);
    csr_j[p] = idx_j[e];
  }
}

// ---------------- single-pass softmax + aggregation (validated r7 form, unchanged) ----------------
__global__ __launch_bounds__(256) void k_aggregate(const int* __restrict__ offsets,
                                                   const int* __restrict__ csr_j,
                                                   const float* __restrict__ asrc,
                                                   const float* __restrict__ adst,
                                                   const unsigned short* __restrict__ Wh,
                                                   float* __restrict__ out, int N) {
  int t = threadIdx.x;
  int wv = t >> 6, l = t & 63;
  int half = l >> 5, ll = l & 31;
  int i = blockIdx.x * 8 + wv * 2 + half;
  bool valid = i < N;
  int beg = (valid && i > 0) ? offsets[i - 1] : 0;
  int end = valid ? offsets[i] : 0;
  int deg = end - beg;
  int hh = ll >> 3;
  float aih = valid ? asrc[i * 4 + hh] : 0.f;

  float o[8];
#pragma unroll
  for (int d = 0; d < 8; ++d) o[d] = 0.f;
  float denom = 0.f;

  for (int q = 0; q < deg; q += 8) {
    int jj[8];
    float wgt[8];
    uint4 vv[8];
#pragma unroll
    for (int k = 0; k < 8; ++k) {
      int qk = q + k;
      int qc = qk < deg - 1 ? qk : deg - 1;
      jj[k] = csr_j[beg + qc];
    }
#pragma unroll
    for (int k = 0; k < 8; ++k) {
      float s = aih + adst[(size_t)jj[k] * 4 + hh];
      s = s > 0.f ? s : NEG_SLOPE * s;
      s = (q + k < deg) ? s : -1e38f;
      wgt[k] = __expf(s);
      vv[k] = *(const uint4*)(Wh + (size_t)jj[k] * 256 + ll * 8);
    }
    denom += ((wgt[0] + wgt[1]) + (wgt[2] + wgt[3])) +
             ((wgt[4] + wgt[5]) + (wgt[6] + wgt[7]));
#pragma unroll
    for (int k = 0; k < 8; ++k) {
      union { uint32_t u; float f; } c0, c1, c2, c3, c4, c5, c6, c7;
      c0.u = vv[k].x << 16; c1.u = vv[k].x & 0xffff0000u;
      c2.u = vv[k].y << 16; c3.u = vv[k].y & 0xffff0000u;
      c4.u = vv[k].z << 16; c5.u = vv[k].z & 0xffff0000u;
      c6.u = vv[k].w << 16; c7.u = vv[k].w & 0xffff0000u;
      float wk = wgt[k];
      o[0] += wk * c0.f; o[1] += wk * c1.f;
      o[2] += wk * c2.f; o[3] += wk * c3.f;
      o[4] += wk * c4.f; o[5] += wk * c5.f;
      o[6] += wk * c6.f; o[7] += wk * c7.f;
    }
  }

  if (valid) {
    float inv = (deg > 0) ? 1.f / denom : 0.f;
    f32x4 o0 = {o[0] * inv, o[1] * inv, o[2] * inv, o[3] * inv};
    f32x4 o1 = {o[4] * inv, o[5] * inv, o[6] * inv, o[7] * inv};
    f32x4* dst = (f32x4*)(out + (size_t)i * 256 + ll * 8);
    __builtin_nontemporal_store(o0, dst);
    __builtin_nontemporal_store(o1, dst + 1);
  }
}

// ---------------- launcher ----------------
extern "C" void kernel_launch(void* const* d_in, const int* in_sizes, int n_in,
                              void* d_out, int out_size, void* d_ws, size_t ws_size,
                              hipStream_t stream) {
  const float* h     = (const float*)d_in[0];
  const int*   eidx  = (const int*)  d_in[1];
  const float* W     = (const float*)d_in[2];
  const float* b     = (const float*)d_in[3];
  const float* a_src = (const float*)d_in[4];
  const float* a_dst = (const float*)d_in[5];
  float* out = (float*)d_out;

  const int N = in_sizes[0] / IN_DIM;
  const int E = in_sizes[1] / 2;
  const int* idx_i = eidx;       // edge_index[0] = destinations
  const int* idx_j = eidx + E;   // edge_index[1] = sources

  char* p = (char*)d_ws;
  auto alloc = [&](size_t bytes) {
    char* r = p;
    p += (bytes + 255) & ~(size_t)255;
    return r;
  };
  float* csrc = (float*)alloc(8 * sizeof(float));
  unsigned short* Wb = (unsigned short*)alloc((size_t)OUT_DIM * IN_DIM * sizeof(unsigned short));
  unsigned short* Wh = (unsigned short*)alloc((size_t)N * OUT_DIM * sizeof(unsigned short));
  float* asrc = (float*)alloc((size_t)N * HEADS * sizeof(float));
  float* adst = (float*)alloc((size_t)N * HEADS * sizeof(float));
  int* counts  = (int*)alloc((size_t)N * sizeof(int));
  int* offsets = (int*)alloc(((size_t)N + 1) * sizeof(int));
  int* bsum    = (int*)alloc(256 * sizeof(int));
  int* csrj    = (int*)alloc((size_t)E * sizeof(int));

  const int nbN = (N + 255) / 256;
  const int nbM = (N + 63) / 64;

  k_prep<<<nbN, 256, 0, stream>>>(W, b, a_src, a_dst, csrc, Wb, counts, N);
  k_gemm_mfma<<<nbM, 256, 0, stream>>>(h, Wb, b, a_src, a_dst, csrc,
                                       Wh, asrc, adst, idx_i, counts, N, E);
  {
    int Nv = N, Ev = E;
    void* args[] = {(void*)&idx_i, (void*)&idx_j, (void*)&counts, (void*)&offsets,
                    (void*)&bsum, (void*)&csrj, (void*)&Nv, (void*)&Ev};
    (void)hipLaunchCooperativeKernel((void*)k_csr, dim3(1024), dim3(256),
                                     args, 0, stream);
  }
  k_aggregate<<<(N + 7) / 8, 256, 0, stream>>>(offsets, csrj, asrc, adst, Wh, out, N);
}

// Round 11
// 193.508 us; speedup vs baseline: 2.2026x; 2.2026x over previous
//
#include <hip/hip_runtime.h>
#include <hip/hip_bf16.h>
#include <stdint.h>

constexpr int IN_DIM  = 256;
constexpr int OUT_DIM = 256;
constexpr int HEADS   = 4;
constexpr int HEAD_DIM = 64;
constexpr float NEG_SLOPE = 0.2f;

typedef __attribute__((ext_vector_type(8))) short bf16x8;
typedef __attribute__((ext_vector_type(4))) float f32x4;

static __device__ __forceinline__ unsigned short f2bf(float f) {
  union { float f; uint32_t u; } v; v.f = f;
  uint32_t u = v.u;
  return (unsigned short)((u + 0x7fffu + ((u >> 16) & 1u)) >> 16);  // RNE
}

// ---------------- prep: zero counts + Wb=bf16(W) (blocks 0..31) + csrc (block 32) ----------------
__global__ __launch_bounds__(256) void k_prep(
    const float* __restrict__ W, const float* __restrict__ b,
    const float* __restrict__ a_src, const float* __restrict__ a_dst,
    float* __restrict__ csrc, unsigned short* __restrict__ Wb,
    int* __restrict__ counts, int N) {
  int bid = blockIdx.x, t = threadIdx.x;
  int i = bid * 256 + t;
  if (i < N) counts[i] = 0;
  if (bid < 32) {
    int base = bid * 2048 + t * 8;
    float4 f0 = *(const float4*)(W + base);
    float4 f1 = *(const float4*)(W + base + 4);
    union { unsigned short us[8]; uint4 u4; } pk;
    pk.us[0]=f2bf(f0.x); pk.us[1]=f2bf(f0.y); pk.us[2]=f2bf(f0.z); pk.us[3]=f2bf(f0.w);
    pk.us[4]=f2bf(f1.x); pk.us[5]=f2bf(f1.y); pk.us[6]=f2bf(f1.z); pk.us[7]=f2bf(f1.w);
    *(uint4*)(Wb + base) = pk.u4;
  } else if (bid == 32 && t < 8) {
    int hh = t & 3;
    const float* a = (t < 4 ? a_src : a_dst) + hh * HEAD_DIM;
    float cs = 0.f;
    for (int d = 0; d < HEAD_DIM; ++d) cs += b[hh * HEAD_DIM + d] * a[d];
    csrc[t] = cs;
  }
}

// ---------------- MFMA GEMM: Wh = bf16( h @ W^T + b ), fused alpha + fused hist ----------------
// tile 64(M) x 256(N), K=256 in 4 chunks of 64. wave w owns cols [w*64,w*64+64) == head w.
// A+B staged in LDS (40KB single-buffered); 16B chunks XOR-swizzled (pos = chunk^(row&7)).
// T14 async-split on A: next chunk's loads issue into registers before compute; the
// convert+LDS-write lands after the post-compute barrier (latency hidden under MFMAs).
// hist fused in the tail: hides the random-atomic pass under the GEMM dispatch (r7-proven).
__global__ __launch_bounds__(256) void k_gemm_mfma(
    const float* __restrict__ h, const unsigned short* __restrict__ Wb,
    const float* __restrict__ b,
    const float* __restrict__ a_src, const float* __restrict__ a_dst,
    const float* __restrict__ csrc,
    unsigned short* __restrict__ Wh,
    float* __restrict__ asrc, float* __restrict__ adst,
    const int* __restrict__ idx_i, int* __restrict__ counts, int N, int E) {
  __shared__ unsigned short lds[20480];  // A @ 0 (8KB), B @ 4096 (32KB)
  const int t = threadIdx.x;
  const int w = t >> 6, l = t & 63;
  const int lm = l & 15, g = l >> 4;
  const int r0 = blockIdx.x * 64;

  const int arow = t >> 2;
  int growA = r0 + arow; if (growA > N - 1) growA = N - 1;
  const float* aptr = h + (size_t)growA * 256;

  f32x4 acc[4][4];
  const f32x4 fz = {0.f, 0.f, 0.f, 0.f};
#pragma unroll
  for (int fm = 0; fm < 4; ++fm)
#pragma unroll
    for (int fn = 0; fn < 4; ++fn) acc[fm][fn] = fz;

  float breg[4], asg[4], adg[4];
#pragma unroll
  for (int fn = 0; fn < 4; ++fn) {
    breg[fn] = b[w * 64 + fn * 16 + lm];
    asg[fn]  = a_src[w * 64 + fn * 16 + lm];
    adg[fn]  = a_dst[w * 64 + fn * 16 + lm];
  }

  f32x4 apre[4];  // prefetched A: 2 chunks x 2 f32x4

  auto loadA = [&](int ch) {  // issue only - no use until writeA
    int k0 = ch * 64;
#pragma unroll
    for (int cc = 0; cc < 2; ++cc) {
      int c = (t & 3) * 2 + cc;
      apre[cc * 2 + 0] = *(const f32x4*)(aptr + k0 + c * 8);
      apre[cc * 2 + 1] = *(const f32x4*)(aptr + k0 + c * 8 + 4);
    }
  };

  auto writeA = [&]() {  // convert + LDS write (vmcnt waits land here)
    unsigned short* dstbase = lds + arow * 64;
#pragma unroll
    for (int cc = 0; cc < 2; ++cc) {
      int c = (t & 3) * 2 + cc;
      union { unsigned short us[8]; bf16x8 v; } pk;
      f32x4 f0 = apre[cc * 2 + 0], f1 = apre[cc * 2 + 1];
      pk.us[0]=f2bf(f0.x); pk.us[1]=f2bf(f0.y); pk.us[2]=f2bf(f0.z); pk.us[3]=f2bf(f0.w);
      pk.us[4]=f2bf(f1.x); pk.us[5]=f2bf(f1.y); pk.us[6]=f2bf(f1.z); pk.us[7]=f2bf(f1.w);
      *(bf16x8*)(dstbase + ((c ^ (arow & 7)) * 8)) = pk.v;
    }
  };

  auto stageB = [&](int ch) {  // Wb is n-major bf16, L2-resident: load+write inline
    int k0 = ch * 64;
    unsigned short* Bbase = lds + 4096;
    int c  = l & 7;
    int rs = l >> 3;
#pragma unroll
    for (int i = 0; i < 8; ++i) {
      int row = w * 64 + i * 8 + rs;  // row&7 == rs
      bf16x8 v = *(const bf16x8*)(Wb + (size_t)row * 256 + k0 + c * 8);
      *(bf16x8*)(Bbase + row * 64 + ((c ^ rs) * 8)) = v;
    }
  };

  auto compute = [&]() {
    const unsigned short* A = lds;
    const unsigned short* B = lds + 4096;
#pragma unroll
    for (int ks = 0; ks < 2; ++ks) {
      bf16x8 af[4], bfr[4];
#pragma unroll
      for (int fm = 0; fm < 4; ++fm) {
        int row = fm * 16 + lm;
        af[fm] = *(const bf16x8*)(A + row * 64 + (((ks * 4 + g) ^ (row & 7)) * 8));
      }
#pragma unroll
      for (int fn = 0; fn < 4; ++fn) {
        int row = w * 64 + fn * 16 + lm;
        bfr[fn] = *(const bf16x8*)(B + row * 64 + (((ks * 4 + g) ^ (row & 7)) * 8));
      }
#pragma unroll
      for (int fm = 0; fm < 4; ++fm)
#pragma unroll
        for (int fn = 0; fn < 4; ++fn)
          acc[fm][fn] = __builtin_amdgcn_mfma_f32_16x16x32_bf16(
              af[fm], bfr[fn], acc[fm][fn], 0, 0, 0);
    }
  };

  loadA(0); writeA(); stageB(0);
  __syncthreads();
#pragma unroll
  for (int ch = 0; ch < 4; ++ch) {
    if (ch < 3) loadA(ch + 1);     // issue next-chunk A loads (no wait)
    compute();                      // MFMA on current LDS contents
    __syncthreads();                // everyone done reading LDS
    if (ch < 3) {
      writeA();                     // A-load wait lands here (hidden by compute)
      stageB(ch + 1);               // B from L2, short drain
      __syncthreads();
    }
  }

  // ---- epilogue 1: Wh store.  D row = (l>>4)*4+reg, col = l&15 ----
#pragma unroll
  for (int fm = 0; fm < 4; ++fm) {
#pragma unroll
    for (int r = 0; r < 4; ++r) {
      int grow = r0 + fm * 16 + g * 4 + r;
      if (grow < N) {
        size_t rowoff = (size_t)grow * 256;
#pragma unroll
        for (int fn = 0; fn < 4; ++fn) {
          int col = w * 64 + fn * 16 + lm;
          Wh[rowoff + col] = f2bf(acc[fm][fn][r] + breg[fn]);
        }
      }
    }
  }

  // ---- epilogue 2: fused alpha (exact fp32 accumulation; wave w == head w) ----
  float cs = csrc[w], cd = csrc[4 + w];
#pragma unroll
  for (int fm = 0; fm < 4; ++fm) {
#pragma unroll
    for (int r = 0; r < 4; ++r) {
      float ps = acc[fm][0][r] * asg[0] + acc[fm][1][r] * asg[1]
               + acc[fm][2][r] * asg[2] + acc[fm][3][r] * asg[3];
      float pd = acc[fm][0][r] * adg[0] + acc[fm][1][r] * adg[1]
               + acc[fm][2][r] * adg[2] + acc[fm][3][r] * adg[3];
#pragma unroll
      for (int off = 1; off < 16; off <<= 1) {
        ps += __shfl_xor(ps, off, 64);
        pd += __shfl_xor(pd, off, 64);
      }
      if (lm == 0) {
        int grow = r0 + fm * 16 + g * 4 + r;
        if (grow < N) {
          asrc[grow * 4 + w] = ps + cs;
          adst[grow * 4 + w] = pd + cd;
        }
      }
    }
  }

  // ---- fused hist: this block's slice of the edge list (counts pre-zeroed) ----
  {
    long long nb = gridDim.x;
    long long e0 = (long long)blockIdx.x * E / nb;
    long long e1 = ((long long)blockIdx.x + 1) * E / nb;
    for (long long e = e0 + t; e < e1; e += 256)
      atomicAdd(&counts[idx_i[e]], 1);
  }
}

// ---------------- CSR build: scan, grain 4 (1024 elems/block) ----------------
__global__ __launch_bounds__(256) void k_scanA(const int* __restrict__ counts,
                                               int* __restrict__ offsets,
                                               int* __restrict__ bsum, int N) {
  __shared__ int s[256];
  int t = threadIdx.x;
  int base = blockIdx.x * 1024 + t * 4;
  int v[4], sum = 0;
#pragma unroll
  for (int k = 0; k < 4; ++k) {
    v[k] = (base + k < N) ? counts[base + k] : 0;
    sum += v[k];
  }
  s[t] = sum;
  __syncthreads();
  for (int off = 1; off < 256; off <<= 1) {
    int x = (t >= off) ? s[t - off] : 0;
    __syncthreads();
    s[t] += x;
    __syncthreads();
  }
  int pre = s[t] - sum;
#pragma unroll
  for (int k = 0; k < 4; ++k) {
    if (base + k < N) offsets[base + k] = pre;
    pre += v[k];
  }
  if (t == 255) bsum[blockIdx.x] = s[255];
}

__global__ __launch_bounds__(256) void k_scanBC(int* __restrict__ offsets,
                                                const int* __restrict__ bsum,
                                                int nb, int N) {
  __shared__ int s[256];
  int t = threadIdx.x;
  int v = (t < nb) ? bsum[t] : 0;
  s[t] = v;
  __syncthreads();
  for (int off = 1; off < 256; off <<= 1) {
    int x = (t >= off) ? s[t - off] : 0;
    __syncthreads();
    s[t] += x;
    __syncthreads();
  }
  int bid = blockIdx.x;
  int add = (bid > 0) ? s[bid - 1] : 0;
  int base = bid * 1024 + t * 4;
#pragma unroll
  for (int k = 0; k < 4; ++k)
    if (base + k < N) offsets[base + k] += add;
}

// ---------------- scatter: cursor-free (atomic post-increment on offsets) ----------------
// After this kernel, offsets[i] == END of segment i.
__global__ __launch_bounds__(256) void k_scatter(const int* __restrict__ idx_i,
                                                 const int* __restrict__ idx_j,
                                                 int* __restrict__ offsets,
                                                 int* __restrict__ csr_j, int E) {
  int e = blockIdx.x * 256 + threadIdx.x;
  if (e < E) {
    int i = idx_i[e];
    int p = atomicAdd(&offsets[i], 1);
    csr_j[p] = idx_j[e];
  }
}

// ---------------- single-pass softmax + aggregation (validated r7 form, unchanged) ----------------
__global__ __launch_bounds__(256) void k_aggregate(const int* __restrict__ offsets,
                                                   const int* __restrict__ csr_j,
                                                   const float* __restrict__ asrc,
                                                   const float* __restrict__ adst,
                                                   const unsigned short* __restrict__ Wh,
                                                   float* __restrict__ out, int N) {
  int t = threadIdx.x;
  int wv = t >> 6, l = t & 63;
  int half = l >> 5, ll = l & 31;
  int i = blockIdx.x * 8 + wv * 2 + half;
  bool valid = i < N;
  int beg = (valid && i > 0) ? offsets[i - 1] : 0;
  int end = valid ? offsets[i] : 0;
  int deg = end - beg;
  int hh = ll >> 3;
  float aih = valid ? asrc[i * 4 + hh] : 0.f;

  float o[8];
#pragma unroll
  for (int d = 0; d < 8; ++d) o[d] = 0.f;
  float denom = 0.f;

  for (int q = 0; q < deg; q += 8) {
    int jj[8];
    float wgt[8];
    uint4 vv[8];
#pragma unroll
    for (int k = 0; k < 8; ++k) {
      int qk = q + k;
      int qc = qk < deg - 1 ? qk : deg - 1;
      jj[k] = csr_j[beg + qc];
    }
#pragma unroll
    for (int k = 0; k < 8; ++k) {
      float s = aih + adst[(size_t)jj[k] * 4 + hh];
      s = s > 0.f ? s : NEG_SLOPE * s;
      s = (q + k < deg) ? s : -1e38f;
      wgt[k] = __expf(s);
      vv[k] = *(const uint4*)(Wh + (size_t)jj[k] * 256 + ll * 8);
    }
    denom += ((wgt[0] + wgt[1]) + (wgt[2] + wgt[3])) +
             ((wgt[4] + wgt[5]) + (wgt[6] + wgt[7]));
#pragma unroll
    for (int k = 0; k < 8; ++k) {
      union { uint32_t u; float f; } c0, c1, c2, c3, c4, c5, c6, c7;
      c0.u = vv[k].x << 16; c1.u = vv[k].x & 0xffff0000u;
      c2.u = vv[k].y << 16; c3.u = vv[k].y & 0xffff0000u;
      c4.u = vv[k].z << 16; c5.u = vv[k].z & 0xffff0000u;
      c6.u = vv[k].w << 16; c7.u = vv[k].w & 0xffff0000u;
      float wk = wgt[k];
      o[0] += wk * c0.f; o[1] += wk * c1.f;
      o[2] += wk * c2.f; o[3] += wk * c3.f;
      o[4] += wk * c4.f; o[5] += wk * c5.f;
      o[6] += wk * c6.f; o[7] += wk * c7.f;
    }
  }

  if (valid) {
    float inv = (deg > 0) ? 1.f / denom : 0.f;
    f32x4 o0 = {o[0] * inv, o[1] * inv, o[2] * inv, o[3] * inv};
    f32x4 o1 = {o[4] * inv, o[5] * inv, o[6] * inv, o[7] * inv};
    f32x4* dst = (f32x4*)(out + (size_t)i * 256 + ll * 8);
    __builtin_nontemporal_store(o0, dst);
    __builtin_nontemporal_store(o1, dst + 1);
  }
}

// ---------------- launcher ----------------
extern "C" void kernel_launch(void* const* d_in, const int* in_sizes, int n_in,
                              void* d_out, int out_size, void* d_ws, size_t ws_size,
                              hipStream_t stream) {
  const float* h     = (const float*)d_in[0];
  const int*   eidx  = (const int*)  d_in[1];
  const float* W     = (const float*)d_in[2];
  const float* b     = (const float*)d_in[3];
  const float* a_src = (const float*)d_in[4];
  const float* a_dst = (const float*)d_in[5];
  float* out = (float*)d_out;

  const int N = in_sizes[0] / IN_DIM;
  const int E = in_sizes[1] / 2;
  const int* idx_i = eidx;       // edge_index[0] = destinations
  const int* idx_j = eidx + E;   // edge_index[1] = sources

  char* p = (char*)d_ws;
  auto alloc = [&](size_t bytes) {
    char* r = p;
    p += (bytes + 255) & ~(size_t)255;
    return r;
  };
  float* csrc = (float*)alloc(8 * sizeof(float));
  unsigned short* Wb = (unsigned short*)alloc((size_t)OUT_DIM * IN_DIM * sizeof(unsigned short));
  unsigned short* Wh = (unsigned short*)alloc((size_t)N * OUT_DIM * sizeof(unsigned short));
  float* asrc = (float*)alloc((size_t)N * HEADS * sizeof(float));
  float* adst = (float*)alloc((size_t)N * HEADS * sizeof(float));
  int* counts  = (int*)alloc((size_t)N * sizeof(int));
  int* offsets = (int*)alloc(((size_t)N + 1) * sizeof(int));
  int* bsum    = (int*)alloc(256 * sizeof(int));
  int* csrj    = (int*)alloc((size_t)E * sizeof(int));

  const int nbN = (N + 255) / 256;
  const int nbE = (E + 255) / 256;
  const int nbM = (N + 63) / 64;
  const int nbS = (N + 1023) / 1024;

  k_prep<<<nbN, 256, 0, stream>>>(W, b, a_src, a_dst, csrc, Wb, counts, N);
  k_gemm_mfma<<<nbM, 256, 0, stream>>>(h, Wb, b, a_src, a_dst, csrc,
                                       Wh, asrc, adst, idx_i, counts, N, E);
  k_scanA<<<nbS, 256, 0, stream>>>(counts, offsets, bsum, N);
  k_scanBC<<<nbS, 256, 0, stream>>>(offsets, bsum, nbS, N);
  k_scatter<<<nbE, 256, 0, stream>>>(idx_i, idx_j, offsets, csrj, E);
  k_aggregate<<<(N + 7) / 8, 256, 0, stream>>>(offsets, csrj, asrc, adst, Wh, out, N);
}